// Round 6
// baseline (3058.848 us; speedup 1.0000x reference)
//
#include <hip/hip_runtime.h>
#include <hip/hip_fp16.h>
#include <stdint.h>

#define K_DIM 4096
#define N_OUT 4096
#define BM 256
#define BN 128
#define BKB 64  // K-bytes per step (2 MFMA K-slices)

typedef __attribute__((ext_vector_type(4))) int int32x4;
typedef __attribute__((ext_vector_type(16))) int int32x16;

// ---------------- per-token int4 activation quantization ----------------
// x_scale = max(x_max/7, fp16(1e-5)); x_q = clip(rint(x/x_scale), -8, 7).
// All f32; no intermediate fp16 rounding (matches harness np reference).
__global__ __launch_bounds__(256) void quant_x(const float* __restrict__ x,
                                               int8_t* __restrict__ xq,
                                               float* __restrict__ xs) {
  const int row = blockIdx.x;
  const int t = threadIdx.x;
  const float4* xr = (const float4*)(x + (size_t)row * K_DIM);
  float4 v[4];
  float m = 0.f;
#pragma unroll
  for (int i = 0; i < 4; ++i) {
    v[i] = xr[t * 4 + i];
    m = fmaxf(m, fmaxf(fmaxf(fabsf(v[i].x), fabsf(v[i].y)),
                       fmaxf(fabsf(v[i].z), fabsf(v[i].w))));
  }
#pragma unroll
  for (int off = 32; off > 0; off >>= 1) m = fmaxf(m, __shfl_xor(m, off));
  __shared__ float wmax[4];
  if ((t & 63) == 0) wmax[t >> 6] = m;
  __syncthreads();
  m = fmaxf(fmaxf(wmax[0], wmax[1]), fmaxf(wmax[2], wmax[3]));

  const float eps = 1.0013580322265625e-05f;  // fp16(1e-5) as f32
  const float xscale = fmaxf(m / 7.0f, eps);
  if (t == 0) xs[row] = xscale;

  uint32_t p[4];
#pragma unroll
  for (int g = 0; g < 4; ++g) {
    const float* fv = (const float*)&v[g];
    uint32_t w = 0;
#pragma unroll
    for (int j = 0; j < 4; ++j) {
      float r = rintf(fv[j] / xscale);
      r = fminf(fmaxf(r, -8.f), 7.f);
      w |= ((uint32_t)(uint8_t)(int8_t)(int)r) << (8 * j);
    }
    p[g] = w;
  }
  *(uint4*)(xq + (size_t)row * K_DIM + t * 16) = *(uint4*)p;
}

// ---------------- weight pack: int32 -> int8, FRAGMENT-MAJOR ----------------
// block b = nfrag*128 + kslice; each block 1024B in MFMA lane order.
__global__ __launch_bounds__(256) void pack_w(const int* __restrict__ w,
                                              uint32_t* __restrict__ wqf) {
  const int c = blockIdx.x * 256 + threadIdx.x;  // one thread per 16B chunk
  const int blk = c >> 6;
  const int l = c & 63;
  const int row = ((blk >> 7) << 5) + (l & 31);
  const int k = ((blk & 127) << 5) + ((l >> 5) << 4);
  const int4* src = (const int4*)(w + (size_t)row * K_DIM + k);  // 16 ints
  uint32_t p[4];
#pragma unroll
  for (int g = 0; g < 4; ++g) {
    const int4 v = src[g];
    p[g] = (uint32_t)(v.x & 255) | ((uint32_t)(v.y & 255) << 8) |
           ((uint32_t)(v.z & 255) << 16) | ((uint32_t)(v.w & 255) << 24);
  }
  *(uint4*)(wqf + (size_t)c * 4) = *(uint4*)p;
}

// ---------------- i8 GEMM: out = dequant(xq . wq^T) ----------------
// 256x128 tile, 4 waves (2m x 2n), wave tile 128x64, 32x32x32 i8 MFMA.
// A: LDS fragment-contiguous, 2-DEEP pipeline (32KB) -> 4 blocks/CU resident
//    (16 waves/CU, the occupancy lever this round).
// B: fragment-major global -> registers, double-buffered.
// vmcnt ledger (per step): issue {4 A-stage(s+1), 4 B-load(s+1)} at top;
// compute; vmcnt(4) retires exactly A(s+1) (oldest 4); B(s+1) may stay in
// flight (compiler's register-dep wait covers it before next step's MFMA).
// ONE barrier per step; 2-buffer parity makes it also the WAR guard.
__global__ __launch_bounds__(256, 4) void gemm_w4a4(
    const int8_t* __restrict__ xq, const uint8_t* __restrict__ wqf,
    const float* __restrict__ xs, const float* __restrict__ wscale,
    float* __restrict__ out, int M) {
  __shared__ uint8_t lds[2][16384];  // A only

  // r3 swizzle: each XCD owns a 4-wide nt strip (B panels 2MB, L2-resident);
  // 4 consecutive local blocks share one A panel.
  const int bid = blockIdx.x;
  const int xcd = bid & 7;
  const int i_loc = bid >> 3;            // 0..127
  const int mt = i_loc >> 2;             // 0..31
  const int nt = xcd * 4 + (i_loc & 3);  // 0..31
  const int tm = mt * BM;
  const int tn = nt * BN;

  const int t = threadIdx.x;
  const int l = t & 63;
  const int wv = t >> 6;
  const int wm = wv >> 1, wn = wv & 1;

  // A staging source: lane l covers row (l&31), k-bytes (l>>5)*16
  const uint8_t* gA = (const uint8_t*)xq + (size_t)tm * K_DIM +
                      (size_t)(l & 31) * K_DIM + ((l >> 5) << 4);
  // B fragment-major base for this wave's two n-frags
  const int nfrag0 = (tn >> 5) + wn * 2;
  const uint8_t* gB0 = wqf + ((size_t)(nfrag0 * 128) << 10) + l * 16;
  const uint8_t* gB1 = wqf + ((size_t)((nfrag0 + 1) * 128) << 10) + l * 16;

  int32x16 acc[4][2] = {};

  auto stageA = [&](int buf, int ktb) {
#pragma unroll
    for (int j = 0; j < 4; ++j) {
      const int bIdx = j * 4 + wv;  // fa = bIdx>>1, kb = bIdx&1
      __builtin_amdgcn_global_load_lds(
          (const __attribute__((address_space(1))) uint32_t*)(
              gA + (size_t)((bIdx >> 1) * 32) * K_DIM + (bIdx & 1) * 32 + ktb),
          (__attribute__((address_space(3))) uint32_t*)(
              &lds[buf][bIdx * 1024 + l * 16]),
          16, 0, 0);
    }
  };

  // load 4 B frags (n x kb) for K-slice pair starting at kslice s2
  auto loadB = [&](int32x4 (&b)[4], int s2) {
    b[0] = *(const int32x4*)(gB0 + ((size_t)(s2 + 0) << 10));
    b[1] = *(const int32x4*)(gB0 + ((size_t)(s2 + 1) << 10));
    b[2] = *(const int32x4*)(gB1 + ((size_t)(s2 + 0) << 10));
    b[3] = *(const int32x4*)(gB1 + ((size_t)(s2 + 1) << 10));
  };

  // one K-step: prefetch (s+1) first, consume A(s) from LDS + bCur from regs.
  auto do_step = [&](int s, int32x4 (&bCur)[4], int32x4 (&bNext)[4]) {
    const int sw = (s + 1) & 63;        // wrapped prefetch index
    stageA((s + 1) & 1, sw * BKB);      // 4 x global_load_lds -> other buffer
    loadB(bNext, sw * 2);               // 4 global loads -> other reg set
    const int buf = s & 1;
#pragma unroll
    for (int kb = 0; kb < 2; ++kb) {
      const uint8_t* base = &lds[buf][(wm * 8 + kb) * 1024 + l * 16];
      int32x4 a[4];
#pragma unroll
      for (int m = 0; m < 4; ++m) a[m] = *(const int32x4*)(base + m * 2048);
      __builtin_amdgcn_s_setprio(1);
#pragma unroll
      for (int m = 0; m < 4; ++m) {
        acc[m][0] = __builtin_amdgcn_mfma_i32_32x32x32_i8(a[m], bCur[kb],
                                                          acc[m][0], 0, 0, 0);
        acc[m][1] = __builtin_amdgcn_mfma_i32_32x32x32_i8(a[m], bCur[2 + kb],
                                                          acc[m][1], 0, 0, 0);
      }
      __builtin_amdgcn_s_setprio(0);
    }
    // retire exactly A(s+1) (oldest 4 of the 8 issued this step)
    asm volatile("s_waitcnt vmcnt(4)" ::: "memory");
    __builtin_amdgcn_s_barrier();
  };

  const int nsteps = K_DIM / BKB;  // 64

  // prologue: A(0) staged into buf0; B(0) -> bX
  int32x4 bX[4], bY[4];
  stageA(0, 0);
  loadB(bX, 0);
  asm volatile("s_waitcnt vmcnt(4)" ::: "memory");  // A(0) landed
  __builtin_amdgcn_s_barrier();

  for (int s = 0; s < nsteps; s += 2) {
    do_step(s, bX, bY);      // consumes bX, prefetches into bY
    do_step(s + 1, bY, bX);  // consumes bY, prefetches into bX
  }
  asm volatile("s_waitcnt vmcnt(0)" ::: "memory");  // drain dead prefetches

  // epilogue: dequant + fp16-round, write f32
  const int colbase = tn + wn * 64;
  const int rowbase = tm + wm * 128 + 4 * (l >> 5);
#pragma unroll
  for (int m = 0; m < 4; ++m) {
#pragma unroll
    for (int n = 0; n < 2; ++n) {
      const int col = colbase + n * 32 + (l & 31);
      const float wsc = wscale[col];
#pragma unroll
      for (int j = 0; j < 16; ++j) {
        const int row = rowbase + m * 32 + (j & 3) + 8 * (j >> 2);
        const float val = (float)acc[m][n][j] * (xs[row] * wsc);
        out[(size_t)row * N_OUT + col] = __half2float(__float2half(val));
      }
    }
  }
}

extern "C" void kernel_launch(void* const* d_in, const int* in_sizes, int n_in,
                              void* d_out, int out_size, void* d_ws, size_t ws_size,
                              hipStream_t stream) {
  const float* x = (const float*)d_in[0];    // fp16 values as f32
  const int* w = (const int*)d_in[1];        // int4-range values as i32
  const float* wsc = (const float*)d_in[2];  // fp16 values as f32
  float* out = (float*)d_out;

  const int M = in_sizes[0] / K_DIM;  // 8192 tokens

  uint8_t* ws = (uint8_t*)d_ws;
  int8_t* xq = (int8_t*)ws;                              // M*K bytes
  uint8_t* wqf = ws + (size_t)M * K_DIM;                 // N*K bytes (frag-major)
  float* xs = (float*)(ws + (size_t)M * K_DIM + (size_t)N_OUT * K_DIM);

  quant_x<<<M, 256, 0, stream>>>(x, xq, xs);
  pack_w<<<(N_OUT * K_DIM / 16) / 256, 256, 0, stream>>>(w, (uint32_t*)wqf);
  gemm_w4a4<<<(M / BM) * (N_OUT / BN), 256, 0, stream>>>(
      xq, wqf, xs, wsc, out, M);
}

// Round 7
// 236.089 us; speedup vs baseline: 12.9563x; 12.9563x over previous
//
#include <hip/hip_runtime.h>
#include <hip/hip_fp16.h>
#include <stdint.h>

#define K_DIM 4096
#define N_OUT 4096
#define BM 256
#define BN 256
#define BKB 128  // K-bytes per step = 4 MFMA K-slices

typedef __attribute__((ext_vector_type(4))) int int32x4;
typedef __attribute__((ext_vector_type(16))) int int32x16;

// ---------------- per-token int4 activation quantization ----------------
// x_scale = max(x_max/7, fp16(1e-5)); x_q = clip(rint(x/x_scale), -8, 7).
// All f32; no intermediate fp16 rounding (matches harness np reference).
__global__ __launch_bounds__(256) void quant_x(const float* __restrict__ x,
                                               int8_t* __restrict__ xq,
                                               float* __restrict__ xs) {
  const int row = blockIdx.x;
  const int t = threadIdx.x;
  const float4* xr = (const float4*)(x + (size_t)row * K_DIM);
  float4 v[4];
  float m = 0.f;
#pragma unroll
  for (int i = 0; i < 4; ++i) {
    v[i] = xr[t * 4 + i];
    m = fmaxf(m, fmaxf(fmaxf(fabsf(v[i].x), fabsf(v[i].y)),
                       fmaxf(fabsf(v[i].z), fabsf(v[i].w))));
  }
#pragma unroll
  for (int off = 32; off > 0; off >>= 1) m = fmaxf(m, __shfl_xor(m, off));
  __shared__ float wmax[4];
  if ((t & 63) == 0) wmax[t >> 6] = m;
  __syncthreads();
  m = fmaxf(fmaxf(wmax[0], wmax[1]), fmaxf(wmax[2], wmax[3]));

  const float eps = 1.0013580322265625e-05f;  // fp16(1e-5) as f32
  const float xscale = fmaxf(m / 7.0f, eps);
  if (t == 0) xs[row] = xscale;

  uint32_t p[4];
#pragma unroll
  for (int g = 0; g < 4; ++g) {
    const float* fv = (const float*)&v[g];
    uint32_t w = 0;
#pragma unroll
    for (int j = 0; j < 4; ++j) {
      float r = rintf(fv[j] / xscale);
      r = fminf(fmaxf(r, -8.f), 7.f);
      w |= ((uint32_t)(uint8_t)(int8_t)(int)r) << (8 * j);
    }
    p[g] = w;
  }
  *(uint4*)(xq + (size_t)row * K_DIM + t * 16) = *(uint4*)p;
}

// ---------------- weight pack: int32 -> int8, FRAGMENT-MAJOR ----------------
// block b = nfrag*128 + kslice; each block 1024B in MFMA lane order.
__global__ __launch_bounds__(256) void pack_w(const int* __restrict__ w,
                                              uint32_t* __restrict__ wqf) {
  const int c = blockIdx.x * 256 + threadIdx.x;  // one thread per 16B chunk
  const int blk = c >> 6;
  const int l = c & 63;
  const int row = ((blk >> 7) << 5) + (l & 31);
  const int k = ((blk & 127) << 5) + ((l >> 5) << 4);
  const int4* src = (const int4*)(w + (size_t)row * K_DIM + k);  // 16 ints
  uint32_t p[4];
#pragma unroll
  for (int g = 0; g < 4; ++g) {
    const int4 v = src[g];
    p[g] = (uint32_t)(v.x & 255) | ((uint32_t)(v.y & 255) << 8) |
           ((uint32_t)(v.z & 255) << 16) | ((uint32_t)(v.w & 255) << 24);
  }
  *(uint4*)(wqf + (size_t)c * 4) = *(uint4*)p;
}

// ---------------- i8 GEMM: out = dequant(xq . wq^T) ----------------
// 256x256 tile, 8 waves (2m x 4n, 512 thr), wave tile 128x64, 32x32x32 i8.
// A: LDS fragment-contiguous, 2-deep (2x32KB), global_load_lds.
// B: fragment-major global -> registers, double-buffered (bX/bY, static).
// Per step (BKB=128 = 4 kslices): prefetch ALL of step s+1 at top
// (4 A-stages then 8 B-loads, order pinned), then 4 phases of
// {4 ds_read -> s_barrier -> setprio + 8 MFMA + setprio -> s_barrier},
// then vmcnt(8): retires exactly A(s+1) (oldest 4), B(s+1) stays in flight
// (compiler reg-dep wait covers it next step). Never vmcnt(0) in the loop.
__global__ __launch_bounds__(512, 2) void gemm_w4a4(
    const int8_t* __restrict__ xq, const uint8_t* __restrict__ wqf,
    const float* __restrict__ xs, const float* __restrict__ wscale,
    float* __restrict__ out, int M) {
  __shared__ uint8_t lds[2][32768];  // A only: 32 frag-blocks (8 fa x 4 ks)/buf

  // Swizzle: A-panels are XCD-exclusive (fetched ~once per XCD, L2-resident);
  // nt varies across i_loc so concurrent blocks in an XCD share A via L2.
  const int bid = blockIdx.x;
  const int xcd = bid & 7;
  const int i_loc = bid >> 3;             // 0..63
  const int mt = xcd * 4 + (i_loc & 3);   // 0..31, XCD-exclusive
  const int nt = i_loc >> 2;              // 0..15
  const int tm = mt * BM;
  const int tn = nt * BN;

  const int t = threadIdx.x;  // 0..511
  const int l = t & 63;
  const int wv = t >> 6;      // 0..7
  const int wm = wv >> 2;     // 0..1
  const int wn = wv & 3;      // 0..3

  // A staging source: lane l covers row (l&31), k-bytes (l>>5)*16
  const uint8_t* gA = (const uint8_t*)xq + (size_t)tm * K_DIM +
                      (size_t)(l & 31) * K_DIM + ((l >> 5) << 4);
  // B fragment-major bases for this wave's two n-frags
  const int nfrag0 = nt * 8 + wn * 2;
  const uint8_t* gB0 = wqf + ((size_t)(nfrag0 * 128) << 10) + l * 16;
  const uint8_t* gB1 = wqf + ((size_t)((nfrag0 + 1) * 128) << 10) + l * 16;

  int32x16 acc[4][2] = {};

  // stage quarter q of step tile (ktb) into buf: block bIdx = q*8 + wv,
  // LDS dest = bIdx*1024 + l*16 = q*8192 + t*16 (linear in t, as required).
  auto stageQ = [&](int buf, int ktb, int q) {
    const int bIdx = q * 8 + wv;
    const int fa = bIdx >> 2, ks = bIdx & 3;
    __builtin_amdgcn_global_load_lds(
        (const __attribute__((address_space(1))) uint32_t*)(
            gA + (size_t)(fa * 32) * K_DIM + ks * 32 + ktb),
        (__attribute__((address_space(3))) uint32_t*)(
            &lds[buf][q * 8192 + t * 16]),
        16, 0, 0);
  };

  // load 8 B frags (2 nfrag x 4 ks) for step sw
  auto loadB = [&](int32x4 (&b)[8], int sw) {
#pragma unroll
    for (int ks = 0; ks < 4; ++ks) {
      b[ks] = *(const int32x4*)(gB0 + ((size_t)(sw * 4 + ks) << 10));
      b[4 + ks] = *(const int32x4*)(gB1 + ((size_t)(sw * 4 + ks) << 10));
    }
  };

  // one phase: ds_read 4 A-frags of kslice ks -> barrier -> 8 MFMA -> barrier
  auto phase = [&](int buf, int ks, int32x4 (&bC)[8]) {
    const uint8_t* base = &lds[buf][wm * 16384 + ks * 1024 + l * 16];
    int32x4 a[4];
#pragma unroll
    for (int m = 0; m < 4; ++m) a[m] = *(const int32x4*)(base + m * 4096);
    __builtin_amdgcn_s_barrier();
    __builtin_amdgcn_s_setprio(1);
#pragma unroll
    for (int m = 0; m < 4; ++m) {
      acc[m][0] = __builtin_amdgcn_mfma_i32_32x32x32_i8(a[m], bC[ks],
                                                        acc[m][0], 0, 0, 0);
      acc[m][1] = __builtin_amdgcn_mfma_i32_32x32x32_i8(a[m], bC[4 + ks],
                                                        acc[m][1], 0, 0, 0);
    }
    __builtin_amdgcn_s_setprio(0);
    __builtin_amdgcn_s_barrier();
  };

  // one step: prefetch s+1 (A then B, order pinned), 4 phases, counted vmcnt
  auto do_step = [&](int s, int32x4 (&bCur)[8], int32x4 (&bNext)[8]) {
    const int sw = (s + 1) & 31;  // wrapped prefetch index (dead at tail)
    const int nbuf = (s + 1) & 1;
#pragma unroll
    for (int q = 0; q < 4; ++q) stageQ(nbuf, sw * BKB, q);
    asm volatile("" ::: "memory");  // pin order: A-stages before B-loads
    loadB(bNext, sw);
    const int buf = s & 1;
    phase(buf, 0, bCur);
    phase(buf, 1, bCur);
    phase(buf, 2, bCur);
    phase(buf, 3, bCur);
    // retire exactly A(s+1): queue = [A(s+1) x4, B(s+1) x8]
    asm volatile("s_waitcnt vmcnt(8)" ::: "memory");
    __builtin_amdgcn_s_barrier();
  };

  const int nsteps = K_DIM / BKB;  // 32

  // prologue: A(0) + B(0); vmcnt(8) retires A(0), B(0) covered by reg-dep
  int32x4 bX[8], bY[8];
#pragma unroll
  for (int q = 0; q < 4; ++q) stageQ(0, 0, q);
  asm volatile("" ::: "memory");
  loadB(bX, 0);
  asm volatile("s_waitcnt vmcnt(8)" ::: "memory");
  __builtin_amdgcn_s_barrier();

  for (int s = 0; s < nsteps; s += 2) {
    do_step(s, bX, bY);      // consumes bX, prefetches into bY
    do_step(s + 1, bY, bX);  // consumes bY, prefetches into bX
  }
  asm volatile("s_waitcnt vmcnt(0)" ::: "memory");  // drain dead prefetches

  // epilogue: dequant + fp16-round, write f32
  const int colbase = tn + wn * 64;
  const int rowbase = tm + wm * 128 + 4 * (l >> 5);
#pragma unroll
  for (int m = 0; m < 4; ++m) {
#pragma unroll
    for (int n = 0; n < 2; ++n) {
      const int col = colbase + n * 32 + (l & 31);
      const float wsc = wscale[col];
#pragma unroll
      for (int j = 0; j < 16; ++j) {
        const int row = rowbase + m * 32 + (j & 3) + 8 * (j >> 2);
        const float val = (float)acc[m][n][j] * (xs[row] * wsc);
        out[(size_t)row * N_OUT + col] = __half2float(__float2half(val));
      }
    }
  }
}

extern "C" void kernel_launch(void* const* d_in, const int* in_sizes, int n_in,
                              void* d_out, int out_size, void* d_ws, size_t ws_size,
                              hipStream_t stream) {
  const float* x = (const float*)d_in[0];    // fp16 values as f32
  const int* w = (const int*)d_in[1];        // int4-range values as i32
  const float* wsc = (const float*)d_in[2];  // fp16 values as f32
  float* out = (float*)d_out;

  const int M = in_sizes[0] / K_DIM;  // 8192 tokens

  uint8_t* ws = (uint8_t*)d_ws;
  int8_t* xq = (int8_t*)ws;                              // M*K bytes
  uint8_t* wqf = ws + (size_t)M * K_DIM;                 // N*K bytes (frag-major)
  float* xs = (float*)(ws + (size_t)M * K_DIM + (size_t)N_OUT * K_DIM);

  quant_x<<<M, 256, 0, stream>>>(x, xq, xs);
  pack_w<<<(N_OUT * K_DIM / 16) / 256, 256, 0, stream>>>(w, (uint32_t*)wqf);
  gemm_w4a4<<<(M / BM) * (N_OUT / BN), 512, 0, stream>>>(
      xq, wqf, xs, wsc, out, M);
}

// Round 8
// 206.663 us; speedup vs baseline: 14.8011x; 1.1424x over previous
//
#include <hip/hip_runtime.h>
#include <hip/hip_fp16.h>
#include <stdint.h>

#define K_DIM 4096
#define N_OUT 4096
#define BM 256
#define BN 256
#define BKB 128  // K-bytes per step = 4 MFMA K-slices

typedef __attribute__((ext_vector_type(4))) int int32x4;
typedef __attribute__((ext_vector_type(16))) int int32x16;

// ---------------- per-token int4 activation quantization ----------------
// x_scale = max(x_max/7, fp16(1e-5)); x_q = clip(rint(x/x_scale), -8, 7).
// All f32; no intermediate fp16 rounding (matches harness np reference).
__global__ __launch_bounds__(256) void quant_x(const float* __restrict__ x,
                                               int8_t* __restrict__ xq,
                                               float* __restrict__ xs) {
  const int row = blockIdx.x;
  const int t = threadIdx.x;
  const float4* xr = (const float4*)(x + (size_t)row * K_DIM);
  float4 v[4];
  float m = 0.f;
#pragma unroll
  for (int i = 0; i < 4; ++i) {
    v[i] = xr[t * 4 + i];
    m = fmaxf(m, fmaxf(fmaxf(fabsf(v[i].x), fabsf(v[i].y)),
                       fmaxf(fabsf(v[i].z), fabsf(v[i].w))));
  }
#pragma unroll
  for (int off = 32; off > 0; off >>= 1) m = fmaxf(m, __shfl_xor(m, off));
  __shared__ float wmax[4];
  if ((t & 63) == 0) wmax[t >> 6] = m;
  __syncthreads();
  m = fmaxf(fmaxf(wmax[0], wmax[1]), fmaxf(wmax[2], wmax[3]));

  const float eps = 1.0013580322265625e-05f;  // fp16(1e-5) as f32
  const float xscale = fmaxf(m / 7.0f, eps);
  if (t == 0) xs[row] = xscale;

  uint32_t p[4];
#pragma unroll
  for (int g = 0; g < 4; ++g) {
    const float* fv = (const float*)&v[g];
    uint32_t w = 0;
#pragma unroll
    for (int j = 0; j < 4; ++j) {
      float r = rintf(fv[j] / xscale);
      r = fminf(fmaxf(r, -8.f), 7.f);
      w |= ((uint32_t)(uint8_t)(int8_t)(int)r) << (8 * j);
    }
    p[g] = w;
  }
  *(uint4*)(xq + (size_t)row * K_DIM + t * 16) = *(uint4*)p;
}

// ---------------- weight pack: int32 -> int8, FRAGMENT-MAJOR ----------------
// block b = nfrag*128 + kslice; each block 1024B in MFMA lane order.
__global__ __launch_bounds__(256) void pack_w(const int* __restrict__ w,
                                              uint32_t* __restrict__ wqf) {
  const int c = blockIdx.x * 256 + threadIdx.x;  // one thread per 16B chunk
  const int blk = c >> 6;
  const int l = c & 63;
  const int row = ((blk >> 7) << 5) + (l & 31);
  const int k = ((blk & 127) << 5) + ((l >> 5) << 4);
  const int4* src = (const int4*)(w + (size_t)row * K_DIM + k);  // 16 ints
  uint32_t p[4];
#pragma unroll
  for (int g = 0; g < 4; ++g) {
    const int4 v = src[g];
    p[g] = (uint32_t)(v.x & 255) | ((uint32_t)(v.y & 255) << 8) |
           ((uint32_t)(v.z & 255) << 16) | ((uint32_t)(v.w & 255) << 24);
  }
  *(uint4*)(wqf + (size_t)c * 4) = *(uint4*)p;
}

// ---------------- i8 GEMM: out = dequant(xq . wq^T) ----------------
// 256x256 tile, 8 waves (2m x 4n, 512 thr), wave tile 128x64, 32x32x32 i8.
// A: LDS fragment-contiguous, 2-deep (2x32KB), global_load_lds.
// B: fragment-major global -> registers, double-buffered (bX/bY, static).
// ZERO internal barriers per step: each step's buffer is fully landed before
// the step starts (vmcnt+barrier at step boundary) and staging targets the
// other buffer, so the 16 ds_read + 32 MFMA body has no block-wide hazards —
// the compiler interleaves ds_read into the MFMA stream with fine-grained
// lgkmcnt, and the 2 waves/SIMD drift to cover each other's stalls.
// a-regs hand-rotated 2-deep (static indices): load a(ks+1) before MFMA(ks).
// vmcnt ledger: per-step queue = [A(s+1) x4, B(s+1) x8]; vmcnt(8) at step end
// retires exactly A(s+1); B(s+1) covered by compiler reg-dep wait next step.
__global__ __launch_bounds__(512, 2) void gemm_w4a4(
    const int8_t* __restrict__ xq, const uint8_t* __restrict__ wqf,
    const float* __restrict__ xs, const float* __restrict__ wscale,
    float* __restrict__ out, int M) {
  __shared__ uint8_t lds[2][32768];  // A only: 32 frag-blocks (8 fa x 4 ks)/buf

  // Swizzle: A-panels XCD-exclusive (L2-resident); concurrent blocks in an
  // XCD share A via L2.
  const int bid = blockIdx.x;
  const int xcd = bid & 7;
  const int i_loc = bid >> 3;            // 0..63
  const int mt = xcd * 4 + (i_loc & 3);  // 0..31, XCD-exclusive
  const int nt = i_loc >> 2;             // 0..15
  const int tm = mt * BM;
  const int tn = nt * BN;

  const int t = threadIdx.x;  // 0..511
  const int l = t & 63;
  const int wv = t >> 6;      // 0..7
  const int wm = wv >> 2;     // 0..1
  const int wn = wv & 3;      // 0..3

  // A staging source: lane l covers row (l&31), k-bytes (l>>5)*16
  const uint8_t* gA = (const uint8_t*)xq + (size_t)tm * K_DIM +
                      (size_t)(l & 31) * K_DIM + ((l >> 5) << 4);
  // B fragment-major bases for this wave's two n-frags
  const int nfrag0 = nt * 8 + wn * 2;
  const uint8_t* gB0 = wqf + ((size_t)(nfrag0 * 128) << 10) + l * 16;
  const uint8_t* gB1 = wqf + ((size_t)((nfrag0 + 1) * 128) << 10) + l * 16;

  int32x16 acc[4][2] = {};

  // stage quarter q of step tile (ktb) into buf: block bIdx = q*8 + wv
  // (fa = bIdx>>2, ks = bIdx&3); LDS dest = q*8192 + t*16 (wave-uniform base
  // + lane*16, as global_load_lds requires).
  auto stageQ = [&](int buf, int ktb, int q) {
    const int bIdx = q * 8 + wv;
    const int fa = bIdx >> 2, ks = bIdx & 3;
    __builtin_amdgcn_global_load_lds(
        (const __attribute__((address_space(1))) uint32_t*)(
            gA + (size_t)(fa * 32) * K_DIM + ks * 32 + ktb),
        (__attribute__((address_space(3))) uint32_t*)(
            &lds[buf][q * 8192 + t * 16]),
        16, 0, 0);
  };

  // load 8 B frags (2 nfrag x 4 ks) for step sw
  auto loadB = [&](int32x4 (&b)[8], int sw) {
#pragma unroll
    for (int ks = 0; ks < 4; ++ks) {
      b[ks] = *(const int32x4*)(gB0 + ((size_t)(sw * 4 + ks) << 10));
      b[4 + ks] = *(const int32x4*)(gB1 + ((size_t)(sw * 4 + ks) << 10));
    }
  };

  const int nsteps = K_DIM / BKB;  // 32

  // one step, no internal barriers; a-regs rotate a0/a1 (all static indices)
  auto do_step = [&](int s, int32x4 (&bCur)[8], int32x4 (&bNext)[8]) {
    const int sw = (s + 1) & 31;  // wrapped prefetch index (dead at tail)
    const int nbuf = (s + 1) & 1;
#pragma unroll
    for (int q = 0; q < 4; ++q) stageQ(nbuf, sw * BKB, q);
    asm volatile("" ::: "memory");  // pin order: A-stages before B-loads
    loadB(bNext, sw);

    const uint8_t* base = &lds[s & 1][wm * 16384 + l * 16];
    int32x4 a0[4], a1[4];
#pragma unroll
    for (int m = 0; m < 4; ++m)
      a0[m] = *(const int32x4*)(base + m * 4096 + 0 * 1024);

#define MFMA8(A, ks)                                                       \
  _Pragma("unroll") for (int m = 0; m < 4; ++m) {                          \
    acc[m][0] =                                                            \
        __builtin_amdgcn_mfma_i32_32x32x32_i8(A[m], bCur[ks], acc[m][0],   \
                                              0, 0, 0);                    \
    acc[m][1] = __builtin_amdgcn_mfma_i32_32x32x32_i8(                     \
        A[m], bCur[4 + ks], acc[m][1], 0, 0, 0);                           \
  }

#pragma unroll
    for (int m = 0; m < 4; ++m)
      a1[m] = *(const int32x4*)(base + m * 4096 + 1 * 1024);
    MFMA8(a0, 0);
#pragma unroll
    for (int m = 0; m < 4; ++m)
      a0[m] = *(const int32x4*)(base + m * 4096 + 2 * 1024);
    MFMA8(a1, 1);
#pragma unroll
    for (int m = 0; m < 4; ++m)
      a1[m] = *(const int32x4*)(base + m * 4096 + 3 * 1024);
    MFMA8(a0, 2);
    MFMA8(a1, 3);
#undef MFMA8

    // retire exactly A(s+1): queue = [A(s+1) x4, B(s+1) x8]
    asm volatile("s_waitcnt vmcnt(8)" ::: "memory");
    __builtin_amdgcn_s_barrier();
  };

  // prologue: A(0) + B(0); vmcnt(8) retires A(0)
  int32x4 bX[8], bY[8];
#pragma unroll
  for (int q = 0; q < 4; ++q) stageQ(0, 0, q);
  asm volatile("" ::: "memory");
  loadB(bX, 0);
  asm volatile("s_waitcnt vmcnt(8)" ::: "memory");
  __builtin_amdgcn_s_barrier();

  for (int s = 0; s < nsteps; s += 2) {
    do_step(s, bX, bY);      // consumes bX, prefetches into bY
    do_step(s + 1, bY, bX);  // consumes bY, prefetches into bX
  }
  asm volatile("s_waitcnt vmcnt(0)" ::: "memory");  // drain dead prefetches

  // epilogue: dequant + fp16-round, write f32
  const int colbase = tn + wn * 64;
  const int rowbase = tm + wm * 128 + 4 * (l >> 5);
#pragma unroll
  for (int m = 0; m < 4; ++m) {
#pragma unroll
    for (int n = 0; n < 2; ++n) {
      const int col = colbase + n * 32 + (l & 31);
      const float wsc = wscale[col];
#pragma unroll
      for (int j = 0; j < 16; ++j) {
        const int row = rowbase + m * 32 + (j & 3) + 8 * (j >> 2);
        const float val = (float)acc[m][n][j] * (xs[row] * wsc);
        out[(size_t)row * N_OUT + col] = __half2float(__float2half(val));
      }
    }
  }
}

extern "C" void kernel_launch(void* const* d_in, const int* in_sizes, int n_in,
                              void* d_out, int out_size, void* d_ws, size_t ws_size,
                              hipStream_t stream) {
  const float* x = (const float*)d_in[0];    // fp16 values as f32
  const int* w = (const int*)d_in[1];        // int4-range values as i32
  const float* wsc = (const float*)d_in[2];  // fp16 values as f32
  float* out = (float*)d_out;

  const int M = in_sizes[0] / K_DIM;  // 8192 tokens

  uint8_t* ws = (uint8_t*)d_ws;
  int8_t* xq = (int8_t*)ws;                              // M*K bytes
  uint8_t* wqf = ws + (size_t)M * K_DIM;                 // N*K bytes (frag-major)
  float* xs = (float*)(ws + (size_t)M * K_DIM + (size_t)N_OUT * K_DIM);

  quant_x<<<M, 256, 0, stream>>>(x, xq, xs);
  pack_w<<<(N_OUT * K_DIM / 16) / 256, 256, 0, stream>>>(w, (uint32_t*)wqf);
  gemm_w4a4<<<(M / BM) * (N_OUT / BN), 512, 0, stream>>>(
      xq, wqf, xs, wsc, out, M);
}